// Round 13
// baseline (5848.730 us; speedup 1.0000x reference)
//
#include <hip/hip_runtime.h>
#include <math.h>

#define NIT 200
#define NN 128
#define NSUB 4
#define ROWS 32          // NN/NSUB rows per block
#define TI 2
#define TJ 4
#define GIL 16           // ROWS/TI thread-rows
#define GJ 32            // NN/TJ  thread-cols
#define NTHREADS 512
#define NWAVES 8

typedef float f2 __attribute__((ext_vector_type(2)));

// d_ws layout: [0 .. 511] int barrier counters, ONE PER 256B LINE (g*64).
// per group g at WS_BASE + g*GS (floats):
//   R   [2][NSUB][8]   parity-buffered reduce slots          (64)
//   HUu [NSUB][128]    u.x  last row of sub (raw)            (512)
//   HUx [NSUB][128]    xi.x last row of sub (raw)            (512)
//   HP  [NSUB][128]    u_pre.x last row of sub (pre-clamp)   (512)
//   HT  [NSUB][128]    t first row of sub                    (512)
#define WS_BASE 512
#define GS 2112
#define R_OFF 0
#define HUU_OFF 64
#define HUX_OFF 576
#define HP_OFF  1088
#define HT_OFF  1600

__global__ __launch_bounds__(NTHREADS)
void tv_kernel(const float* __restrict__ Min, const float* __restrict__ tvr,
               float* __restrict__ out, int Nb, float* __restrict__ ws)
{
  const float MUc = 0.25f;
  const int bid = blockIdx.x;
  const int g   = bid % Nb;        // batch  (bid%8 -> XCD affinity heuristic)
  const int sub = bid / Nb;        // 0..3 vertical slab
  const int tid = threadIdx.x;
  const int tx  = tid & (GJ - 1);  // 0..31
  const int ty  = tid >> 5;        // 0..15
  const int lane = tid & 63;
  const int wv   = tid >> 6;
  const int j0 = tx * TJ;

  __shared__ float2 m2[(TI * TJ / 2) * NTHREADS];  // 16 KB  slab of M
  __shared__ float2 t2[(TI * TJ / 2) * NTHREADS];  // 16 KB  slab of t
  __shared__ float sTop [TJ][GIL][GJ];             //  8 KB  u.x bottom rows
  __shared__ float sLeft[TI][GIL][GJ];             //  4 KB  u.y right cols
  __shared__ float4 sRedA[2][NWAVES];
  __shared__ float2 sRedB[2][NWAVES];
  __shared__ float sBc[8];                         // group-reduce broadcast

  float* wsg = ws + WS_BASE + (size_t)g * GS;
  int*   cnt = reinterpret_cast<int*>(ws) + (size_t)g * 64;  // 256B apart

  const float r = tvr[0];
  const float mx = (sub == NSUB - 1 && ty == GIL - 1) ? 0.f : 1.f;
  const float my = (tx == GJ - 1) ? 0.f : 1.f;

  f2 u[TI][TJ], xi[TI][TJ];   // 32 VGPRs of state

  const float* Mb = Min + (size_t)g * NN * NN + (size_t)sub * ROWS * NN;
#pragma unroll
  for (int di = 0; di < TI; ++di) {
    float4 v4 = *reinterpret_cast<const float4*>(Mb + (ty * TI + di) * NN + j0);
    m2[(di * 2 + 0) * NTHREADS + tid] = make_float2(v4.x, v4.y);
    m2[(di * 2 + 1) * NTHREADS + tid] = make_float2(v4.z, v4.w);
#pragma unroll
    for (int dj = 0; dj < TJ; ++dj) { u[di][dj] = (f2)0.f; xi[di][dj] = (f2)0.f; }
  }
  __syncthreads();

  // ---- group barrier (monotonic counter; reset by host memset each launch)
  int phase = 0;
  auto gbar = [&]() {
    phase += NSUB;
    __threadfence();          // release this block's global stores
    __syncthreads();
    if (tid == 0) {
      atomicAdd(cnt, 1);
      while (__hip_atomic_load(cnt, __ATOMIC_RELAXED, __HIP_MEMORY_SCOPE_AGENT) < phase)
        __builtin_amdgcn_s_sleep(1);
      __threadfence();        // acquire: see remote stores
    }
    __syncthreads();
  };

  int par = 0;
  auto blk_red4 = [&](float v0, float v1, float v2, float v3) {
#pragma unroll
    for (int off = 32; off >= 1; off >>= 1) {
      v0 += __shfl_xor(v0, off, 64); v1 += __shfl_xor(v1, off, 64);
      v2 += __shfl_xor(v2, off, 64); v3 += __shfl_xor(v3, off, 64);
    }
    if (lane == 0) sRedA[par][wv] = make_float4(v0, v1, v2, v3);
    __syncthreads();
    float4 acc = make_float4(0.f, 0.f, 0.f, 0.f);
#pragma unroll
    for (int w = 0; w < NWAVES; ++w) {
      float4 q = sRedA[par][w];
      acc.x += q.x; acc.y += q.y; acc.z += q.z; acc.w += q.w;
    }
    par ^= 1;
    return acc;
  };
  auto blk_red6 = [&](float s0, float s1, float p0, float p1, float c0, float c1,
                      float4& o4, float2& o2) {
#pragma unroll
    for (int off = 32; off >= 1; off >>= 1) {
      s0 += __shfl_xor(s0, off, 64); s1 += __shfl_xor(s1, off, 64);
      p0 += __shfl_xor(p0, off, 64); p1 += __shfl_xor(p1, off, 64);
      c0 += __shfl_xor(c0, off, 64); c1 += __shfl_xor(c1, off, 64);
    }
    if (lane == 0) {
      sRedA[par][wv] = make_float4(s0, s1, p0, p1);
      sRedB[par][wv] = make_float2(c0, c1);
    }
    __syncthreads();
    float4 a4 = sRedA[par][0]; float2 a2 = sRedB[par][0];
#pragma unroll
    for (int w = 1; w < NWAVES; ++w) {
      float4 q = sRedA[par][w]; float2 h = sRedB[par][w];
      a4.x += q.x; a4.y += q.y; a4.z += q.z; a4.w += q.w;
      a2.x += h.x; a2.y += h.y;
    }
    par ^= 1;
    o4 = a4; o2 = a2;
  };

  // group slot aggregation: wave0 lane-parallel (1 coalesced 128B read),
  // fold subs via 2 shfl_xor, broadcast through LDS.
  auto slot_agg = [&](int rpv) {
    if (wv == 0) {
      float v = (lane < NSUB * 8) ? wsg[R_OFF + (rpv * NSUB) * 8 + lane] : 0.f;
      v += __shfl_xor(v, 8, 64);
      v += __shfl_xor(v, 16, 64);
      if (lane < 8) sBc[lane] = v;
    }
    __syncthreads();
  };

  int rp = 0;
  auto gred4 = [&](float v0, float v1, float v2, float v3) -> float4 {
    float4 loc = blk_red4(v0, v1, v2, v3);
    if (tid == 0) {
      float* sl = wsg + R_OFF + (rp * NSUB + sub) * 8;
      sl[0] = loc.x; sl[1] = loc.y; sl[2] = loc.z; sl[3] = loc.w;
    }
    gbar();
    slot_agg(rp);
    rp ^= 1;
    return make_float4(sBc[0], sBc[1], sBc[2], sBc[3]);
  };
  auto gred6 = [&](float s0, float s1, float p0, float p1, float c0, float c1,
                   float4& o4, float2& o2) {
    float4 l4; float2 l2;
    blk_red6(s0, s1, p0, p1, c0, c1, l4, l2);
    if (tid == 0) {
      float* sl = wsg + R_OFF + (rp * NSUB + sub) * 8;
      sl[0] = l4.x; sl[1] = l4.y; sl[2] = l4.z; sl[3] = l4.w;
      sl[4] = l2.x; sl[5] = l2.y;
    }
    gbar();
    slot_agg(rp);
    rp ^= 1;
    o4 = make_float4(sBc[0], sBc[1], sBc[2], sBc[3]);
    o2 = make_float2(sBc[4], sBc[5]);
  };

  // Duchi threshold solve with fused predictive probe, group-wide.
  auto solve2 = [&](auto&& scan, float S0, float S1, float rad,
                    float psa0, float pc0, float tp0,
                    float psa1, float pc1, float tp1) -> float2 {
    const float invD = 1.f / 16384.f;
    const float TOL = 1e-4f;
    float t0, t1; bool d0 = false, d1 = false;
    float np0 = -1.f, np1 = -1.f;
    if (S0 <= rad) { t0 = 0.f; d0 = true; }
    else {
      float lb = (S0 - rad) * invD;
      if (pc0 < 0.5f) t0 = lb;
      else {
        float tn = tp0 + __fdividef(psa0 - rad, pc0);
        if (tn == tp0 || fabsf(tn - tp0) <= TOL * tp0) { t0 = tn; d0 = true; }
        else { t0 = fmaxf(tn, lb); np0 = pc0; }
      }
    }
    if (S1 <= rad) { t1 = 0.f; d1 = true; }
    else {
      float lb = (S1 - rad) * invD;
      if (pc1 < 0.5f) t1 = lb;
      else {
        float tn = tp1 + __fdividef(psa1 - rad, pc1);
        if (tn == tp1 || fabsf(tn - tp1) <= TOL * tp1) { t1 = tn; d1 = true; }
        else { t1 = fmaxf(tn, lb); np1 = pc1; }
      }
    }
    for (int k = 0; k < 40 && !(d0 && d1); ++k) {
      float sa0 = 0.f, c0 = 0.f, sa1 = 0.f, c1 = 0.f;
      scan(t0, t1, sa0, c0, sa1, c1);
      float4 rd = gred4(sa0, c0, sa1, c1);
      if (!d0) {
        if (rd.y < 0.5f) { t0 = (S0 - rad) * invD; np0 = -1.f; }
        else {
          float tn = __fdividef(rd.x - rad, rd.y);
          if (rd.y == np0 || tn == t0 || fabsf(tn - t0) <= TOL * t0) d0 = true;
          t0 = tn; np0 = rd.y;
        }
      }
      if (!d1) {
        if (rd.w < 0.5f) { t1 = (S1 - rad) * invD; np1 = -1.f; }
        else {
          float tn = __fdividef(rd.z - rad, rd.w);
          if (rd.w == np1 || tn == t1 || fabsf(tn - t1) <= TOL * t1) d1 = true;
          t1 = tn; np1 = rd.w;
        }
      }
    }
    return make_float2(t0, t1);
  };

  auto scanP1 = [&](float t0, float t1, float& sa0, float& c0, float& sa1, float& c1) {
#pragma unroll
    for (int di = 0; di < TI; ++di)
#pragma unroll
      for (int dj = 0; dj < TJ; ++dj) {
        f2 w = u[di][dj] - xi[di][dj];
        float a0v = fabsf(w.x), a1v = fabsf(w.y);
        if (a0v > t0) { sa0 += a0v; c0 += 1.f; }
        if (a1v > t1) { sa1 += a1v; c1 += 1.f; }
      }
  };
  auto scanP3 = [&](float t0, float t1, float& sa0, float& c0, float& sa1, float& c1) {
#pragma unroll
    for (int di = 0; di < TI; ++di)
#pragma unroll
      for (int dj = 0; dj < TJ; ++dj) {
        float a0v = fabsf(u[di][dj].x), a1v = fabsf(u[di][dj].y);
        if (a0v > t0) { sa0 += a0v; c0 += 1.f; }
        if (a1v > t1) { sa1 += a1v; c1 += 1.f; }
      }
  };

  // div: t = m - div(u). uph[4] = up-halo values for ty==0 (pre-transformed).
  auto div_pass = [&](const float* uph) {
    float tr0[TJ];
#pragma unroll
    for (int di = 0; di < TI; ++di) {
#pragma unroll
      for (int q2 = 0; q2 < 2; ++q2) {
        const int dj0 = 2 * q2, dj1 = 2 * q2 + 1;
        float2 mm = m2[(di * 2 + q2) * NTHREADS + tid];
        float up0 = (di > 0) ? u[di - 1][dj0].x
                             : ((ty > 0) ? sTop[dj0][ty - 1][tx] : uph[dj0]);
        float lf0 = (dj0 > 0) ? u[di][dj0 - 1].y
                              : ((tx > 0) ? sLeft[di][ty][tx - 1] : 0.f);
        float vx0 = u[di][dj0].x; if (di == TI - 1) vx0 *= mx;
        float vy0 = u[di][dj0].y;
        float tt0 = mm.x - ((vx0 - up0) + (vy0 - lf0));
        float up1 = (di > 0) ? u[di - 1][dj1].x
                             : ((ty > 0) ? sTop[dj1][ty - 1][tx] : uph[dj1]);
        float lf1 = u[di][dj1 - 1].y;
        float vx1 = u[di][dj1].x; if (di == TI - 1) vx1 *= mx;
        float vy1 = u[di][dj1].y; if (dj1 == TJ - 1) vy1 *= my;
        float tt1 = mm.y - ((vx1 - up1) + (vy1 - lf1));
        t2[(di * 2 + q2) * NTHREADS + tid] = make_float2(tt0, tt1);
        if (di == 0) { tr0[dj0] = tt0; tr0[dj1] = tt1; }
      }
    }
    if (ty == 0)
      *reinterpret_cast<float4*>(wsg + HT_OFF + sub * NN + j0) =
          make_float4(tr0[0], tr0[1], tr0[2], tr0[3]);
  };

  // grad: reads t2 (+ HT[sub+1] down-halo); consume(di,dj,g)
  auto grad_pass = [&](auto&& consume) {
#pragma unroll
    for (int q2 = 0; q2 < 2; ++q2) {
      float2 c0p = t2[(0 * 2 + q2) * NTHREADS + tid];
      float2 c1p = t2[(1 * 2 + q2) * NTHREADS + tid];
      float2 dn1p;
      if (ty < GIL - 1) dn1p = t2[q2 * NTHREADS + tid + GJ];
      else if (sub < NSUB - 1)
        dn1p = *reinterpret_cast<const float2*>(wsg + HT_OFF + (sub + 1) * NN + j0 + 2 * q2);
      else dn1p = make_float2(0.f, 0.f);       // masked by mx anyway
      float rt0, rt1;
      if (q2 < 1) {
        rt0 = t2[(0 * 2 + 1) * NTHREADS + tid].x;
        rt1 = t2[(1 * 2 + 1) * NTHREADS + tid].x;
      } else {
        const int off = (tx < GJ - 1) ? 1 : 0;  // masked by my at tx==GJ-1
        rt0 = t2[(0 * 2 + 0) * NTHREADS + tid + off].x;
        rt1 = t2[(1 * 2 + 0) * NTHREADS + tid + off].x;
      }
      { f2 gg; gg.x = c1p.x - c0p.x; gg.y = c0p.y - c0p.x; consume(0, 2 * q2, gg); }
      { f2 gg; gg.x = c1p.y - c0p.y;
        gg.y = rt0 - c0p.y; if (q2 == 1) gg.y *= my; consume(0, 2 * q2 + 1, gg); }
      { f2 gg; gg.x = (dn1p.x - c1p.x) * mx; gg.y = c1p.y - c1p.x; consume(1, 2 * q2, gg); }
      { f2 gg; gg.x = (dn1p.y - c1p.y) * mx;
        gg.y = rt1 - c1p.y; if (q2 == 1) gg.y *= my; consume(1, 2 * q2 + 1, gg); }
    }
  };

  float A = 0.f;
  float h1x = 0.f, h1y = 0.f, d1x = 0.f, d1y = 0.f;
  float h3x = 0.f, h3y = 0.f, d3x = 0.f, d3y = 0.f;
  float S0p = 0.f, S1p = 0.f, q1s0 = 0.f, q1s1 = 0.f, q1c0 = 0.f, q1c1 = 0.f;
  float t1p0 = 0.f, t1p1 = 0.f;
  float thx, thy;
  const float rad3 = r * (MUc * 0.5f);
  float uph[TJ] = {0.f, 0.f, 0.f, 0.f};

#pragma unroll 1
  for (int it = 0;; ++it) {
    const float a_ = 0.5f * (MUc + sqrtf(MUc * (MUc + 4.f * A)));

    // ---- P1 thresholds
    if (it == 0) { thx = INFINITY; thy = INFINITY; }
    else {
      float2 th = solve2(scanP1, S0p, S1p, r * A,
                         q1s0, q1c0, t1p0, q1s1, q1c1, t1p1);
      thx = th.x; thy = th.y;
      d1x = thx - h1x; d1y = thy - h1y;
      h1x = thx; h1y = thy;
    }

    // ---- P2a: y = cu*u + cv*clamp(u-xi, ±th); local halos
    const float inv = 1.f / (A + a_);
    const float cu = A * inv, cv = a_ * inv;
#pragma unroll
    for (int di = 0; di < TI; ++di)
#pragma unroll
      for (int dj = 0; dj < TJ; ++dj) {
        f2 w = u[di][dj] - xi[di][dj];
        f2 v;
        v.x = __builtin_amdgcn_fmed3f(w.x, -thx, thx);
        v.y = __builtin_amdgcn_fmed3f(w.y, -thy, thy);
        u[di][dj] = u[di][dj] * cu + v * cv;
      }
#pragma unroll
    for (int dj = 0; dj < TJ; ++dj) sTop[dj][ty][tx] = u[TI - 1][dj].x;
#pragma unroll
    for (int di = 0; di < TI; ++di) sLeft[di][ty][tx] = u[di][TJ - 1].y;
    // up-halo for div#1: y of row above from raw (u,xi) written at prev P4b
    if (ty == 0 && sub > 0) {
      float4 hu = *reinterpret_cast<const float4*>(wsg + HUU_OFF + (sub - 1) * NN + j0);
      float4 hx = *reinterpret_cast<const float4*>(wsg + HUX_OFF + (sub - 1) * NN + j0);
      uph[0] = cu * hu.x + cv * __builtin_amdgcn_fmed3f(hu.x - hx.x, -thx, thx);
      uph[1] = cu * hu.y + cv * __builtin_amdgcn_fmed3f(hu.y - hx.y, -thx, thx);
      uph[2] = cu * hu.z + cv * __builtin_amdgcn_fmed3f(hu.z - hx.z, -thx, thx);
      uph[3] = cu * hu.w + cv * __builtin_amdgcn_fmed3f(hu.w - hx.w, -thx, thx);
    }
    __syncthreads();
    div_pass(uph);        // t = M - div(y); writes HT[sub]
    gbar();               // B2: t + HT ready

    // ---- P2b: u_pre = y - (mu/2) grad(t); fused P3 sums + predictive probe
    {
      float s0 = 0.f, s1 = 0.f, p0 = 0.f, p1 = 0.f, c0 = 0.f, c1 = 0.f;
      const float tp0 = fmaxf(0.f, h3x + d3x);
      const float tp1 = fmaxf(0.f, h3y + d3y);
      grad_pass([&](int di, int dj, f2 gg) {
        f2 nu = u[di][dj] - 0.125f * gg;
        u[di][dj] = nu;
        float a0 = fabsf(nu.x), a1 = fabsf(nu.y);
        s0 += a0; s1 += a1;
        if (a0 > tp0) { p0 += a0 - tp0; c0 += 1.f; }
        if (a1 > tp1) { p1 += a1 - tp1; c1 += 1.f; }
      });
      // u_pre.x last-row halo for div#2 (reader clamps with theta3)
      if (ty == GIL - 1)
        *reinterpret_cast<float4*>(wsg + HP_OFF + sub * NN + j0) =
            make_float4(u[1][0].x, u[1][1].x, u[1][2].x, u[1][3].x);
      float4 q4; float2 q2v;
      gred6(s0, s1, p0, p1, c0, c1, q4, q2v);   // B3 (covers HP)
      float2 th3 = solve2(scanP3, q4.x, q4.y, rad3,
                          q4.z, q2v.x, tp0, q4.w, q2v.y, tp1);
      thx = th3.x; thy = th3.y;
      d3x = thx - h3x; d3y = thy - h3y;
      h3x = thx; h3y = thy;
    }
    // ---- P4a: clamp; local halos; up-halo = clamped HP of sub-1
#pragma unroll
    for (int di = 0; di < TI; ++di)
#pragma unroll
      for (int dj = 0; dj < TJ; ++dj) {
        u[di][dj].x = __builtin_amdgcn_fmed3f(u[di][dj].x, -thx, thx);
        u[di][dj].y = __builtin_amdgcn_fmed3f(u[di][dj].y, -thy, thy);
      }
#pragma unroll
    for (int dj = 0; dj < TJ; ++dj) sTop[dj][ty][tx] = u[TI - 1][dj].x;
#pragma unroll
    for (int di = 0; di < TI; ++di) sLeft[di][ty][tx] = u[di][TJ - 1].y;
    if (ty == 0 && sub > 0) {
      float4 hp = *reinterpret_cast<const float4*>(wsg + HP_OFF + (sub - 1) * NN + j0);
      uph[0] = __builtin_amdgcn_fmed3f(hp.x, -thx, thx);
      uph[1] = __builtin_amdgcn_fmed3f(hp.y, -thx, thx);
      uph[2] = __builtin_amdgcn_fmed3f(hp.z, -thx, thx);
      uph[3] = __builtin_amdgcn_fmed3f(hp.w, -thx, thx);
    }
    __syncthreads();
    div_pass(uph);        // t = Mnew; writes HT[sub]
    if (it == NIT - 1) break;
    gbar();               // B4: t + HT ready

    // ---- P4b: xi += a*grad(Mnew); fused next-P1 sums + predictive probe
    {
      float s0 = 0.f, s1 = 0.f, p0 = 0.f, p1 = 0.f, c0 = 0.f, c1 = 0.f;
      t1p0 = fmaxf(0.f, h1x + d1x);
      t1p1 = fmaxf(0.f, h1y + d1y);
      const float tp0 = t1p0, tp1 = t1p1;
      grad_pass([&](int di, int dj, f2 gg) {
        xi[di][dj] = xi[di][dj] + a_ * gg;
        f2 w = u[di][dj] - xi[di][dj];
        float a0 = fabsf(w.x), a1 = fabsf(w.y);
        s0 += a0; s1 += a1;
        if (a0 > tp0) { p0 += a0 - tp0; c0 += 1.f; }
        if (a1 > tp1) { p1 += a1 - tp1; c1 += 1.f; }
      });
      // raw (u, xi) last-row halos for next iter's div#1
      if (ty == GIL - 1) {
        *reinterpret_cast<float4*>(wsg + HUU_OFF + sub * NN + j0) =
            make_float4(u[1][0].x, u[1][1].x, u[1][2].x, u[1][3].x);
        *reinterpret_cast<float4*>(wsg + HUX_OFF + sub * NN + j0) =
            make_float4(xi[1][0].x, xi[1][1].x, xi[1][2].x, xi[1][3].x);
      }
      float4 q4; float2 q2v;
      gred6(s0, s1, p0, p1, c0, c1, q4, q2v);   // B5 (covers HU)
      S0p = q4.x; S1p = q4.y; q1s0 = q4.z; q1s1 = q4.w; q1c0 = q2v.x; q1c1 = q2v.y;
    }
    A += a_;
  }

  // outputs: M1 slab from t2, u slab interleaved
  float* outM = out + (size_t)g * NN * NN + (size_t)sub * ROWS * NN;
  float* outU = out + (size_t)Nb * NN * NN + (size_t)g * NN * NN * 2 + (size_t)sub * ROWS * NN * 2;
#pragma unroll
  for (int di = 0; di < TI; ++di)
#pragma unroll
    for (int q2 = 0; q2 < 2; ++q2) {
      float2 tp = t2[(di * 2 + q2) * NTHREADS + tid];
      const int idx0 = (ty * TI + di) * NN + (j0 + 2 * q2);
      outM[idx0]     = tp.x;
      outM[idx0 + 1] = tp.y;
      reinterpret_cast<float2*>(outU)[idx0]     = make_float2(u[di][2 * q2].x,     u[di][2 * q2].y);
      reinterpret_cast<float2*>(outU)[idx0 + 1] = make_float2(u[di][2 * q2 + 1].x, u[di][2 * q2 + 1].y);
    }
}

extern "C" void kernel_launch(void* const* d_in, const int* in_sizes, int n_in,
                              void* d_out, int out_size, void* d_ws, size_t ws_size,
                              hipStream_t stream) {
  const float* M  = (const float*)d_in[0];
  const float* tv = (const float*)d_in[1];
  const int Nb = in_sizes[0] / (NN * NN);   // 8
  const size_t wneed = (WS_BASE + (size_t)Nb * GS) * sizeof(float);
  hipMemsetAsync(d_ws, 0, wneed, stream);   // zero barrier counters + halos
  tv_kernel<<<dim3(Nb * NSUB), dim3(NTHREADS), 0, stream>>>(
      M, tv, (float*)d_out, Nb, (float*)d_ws);
}

// Round 14
// 1922.502 us; speedup vs baseline: 3.0422x; 3.0422x over previous
//
#include <hip/hip_runtime.h>
#include <math.h>

#define NIT 200
#define NN 128
#define TI 4
#define TJ 8
#define GI 32   // NN/TI
#define GJ 16   // NN/TJ
#define NTHREADS 512
#define NWAVES 8

typedef float f2 __attribute__((ext_vector_type(2)));

__global__ __launch_bounds__(NTHREADS)
void tv_kernel(const float* __restrict__ Min, const float* __restrict__ tvr,
               float* __restrict__ out, int Nb)
{
  const float MUc = 0.25f;
  const int b   = blockIdx.x;
  const int tid = threadIdx.x;
  const int tx  = tid & (GJ - 1);   // 0..15
  const int ty  = tid >> 4;         // 0..31
  const int lane = tid & 63;
  const int wv   = tid >> 6;
  const int i0 = ty * TI;
  const int j0 = tx * TJ;

  // Fields in LDS as float2 pairs [pair][tid]; halo buffers double-duty:
  //   P2a writes y-halos        -> div#1 reads raw
  //   P2b writes u_pre-halos    -> div#2 reads with fmed3(±theta3) at read
  __shared__ float2 m2_lds[(TI * TJ / 2) * NTHREADS];  // 64 KB
  __shared__ float2 t2_lds[(TI * TJ / 2) * NTHREADS];  // 64 KB
  __shared__ float sTop [TJ][GI][GJ];           // 16 KB  (x-comp bottom rows)
  __shared__ float sLeft[TI][GI][GJ];           //  8 KB  (y-comp right cols)
  __shared__ float4 sRedA[2][NWAVES];
  __shared__ float2 sRedB[2][NWAVES];
  // total ~152.5 KB -> 1 block/CU

  const float r = tvr[0];
  const float mx = (ty == GI - 1) ? 0.f : 1.f;
  const float my = (tx == GJ - 1) ? 0.f : 1.f;

  f2 u[TI][TJ], xi[TI][TJ];   // 128 VGPRs of state

  const float* Mb = Min + (size_t)b * NN * NN;
#pragma unroll
  for (int di = 0; di < TI; ++di) {
    float4 v0 = *reinterpret_cast<const float4*>(Mb + (i0 + di) * NN + j0);
    float4 v1 = *reinterpret_cast<const float4*>(Mb + (i0 + di) * NN + j0 + 4);
    m2_lds[(di * 4 + 0) * NTHREADS + tid] = make_float2(v0.x, v0.y);
    m2_lds[(di * 4 + 1) * NTHREADS + tid] = make_float2(v0.z, v0.w);
    m2_lds[(di * 4 + 2) * NTHREADS + tid] = make_float2(v1.x, v1.y);
    m2_lds[(di * 4 + 3) * NTHREADS + tid] = make_float2(v1.z, v1.w);
#pragma unroll
    for (int dj = 0; dj < TJ; ++dj) {
      u[di][dj] = (f2)0.f; xi[di][dj] = (f2)0.f;
    }
  }
  __syncthreads();

  int par = 0;
  auto blk_red4 = [&](float v0, float v1, float v2, float v3) {
#pragma unroll
    for (int off = 32; off >= 1; off >>= 1) {
      v0 += __shfl_xor(v0, off, 64);
      v1 += __shfl_xor(v1, off, 64);
      v2 += __shfl_xor(v2, off, 64);
      v3 += __shfl_xor(v3, off, 64);
    }
    if (lane == 0) sRedA[par][wv] = make_float4(v0, v1, v2, v3);
    __syncthreads();
    float4 acc = make_float4(0.f, 0.f, 0.f, 0.f);
#pragma unroll
    for (int w = 0; w < NWAVES; ++w) {
      float4 q = sRedA[par][w];
      acc.x += q.x; acc.y += q.y; acc.z += q.z; acc.w += q.w;
    }
    par ^= 1;
    return acc;
  };
  auto blk_red6 = [&](float s0, float s1, float p0, float p1, float c0, float c1,
                      float4& o4, float2& o2) {
#pragma unroll
    for (int off = 32; off >= 1; off >>= 1) {
      s0 += __shfl_xor(s0, off, 64); s1 += __shfl_xor(s1, off, 64);
      p0 += __shfl_xor(p0, off, 64); p1 += __shfl_xor(p1, off, 64);
      c0 += __shfl_xor(c0, off, 64); c1 += __shfl_xor(c1, off, 64);
    }
    if (lane == 0) {
      sRedA[par][wv] = make_float4(s0, s1, p0, p1);
      sRedB[par][wv] = make_float2(c0, c1);
    }
    __syncthreads();
    float4 a4 = sRedA[par][0]; float2 a2 = sRedB[par][0];
#pragma unroll
    for (int w = 1; w < NWAVES; ++w) {
      float4 q = sRedA[par][w]; float2 h = sRedB[par][w];
      a4.x += q.x; a4.y += q.y; a4.z += q.z; a4.w += q.w;
      a2.x += h.x; a2.y += h.y;
    }
    par ^= 1;
    o4 = a4; o2 = a2;
  };

  // Duchi threshold solve with fused PREDICTIVE probe. maxk>0 (warm-up):
  // verification scans refine to the exact root. maxk==0 (steady state):
  // single Newton step from the probe (exact global sums at the predicted
  // point); with 2nd-order prediction the step error is O(pred_err^2).
  auto solve2 = [&](auto&& scan, float S0, float S1, float rad,
                    float psa0, float pc0, float tp0,
                    float psa1, float pc1, float tp1, int maxk) -> float2 {
    const float invD = 1.f / 16384.f;
    const float TOL = 1e-4f;
    float t0, t1; bool d0 = false, d1 = false;
    float np0 = -1.f, np1 = -1.f;
    if (S0 <= rad) { t0 = 0.f; d0 = true; }
    else {
      float lb = (S0 - rad) * invD;
      if (pc0 < 0.5f) t0 = lb;
      else {
        float tn = tp0 + __fdividef(psa0 - rad, pc0);
        if (tn == tp0 || fabsf(tn - tp0) <= TOL * tp0) { t0 = tn; d0 = true; }
        else { t0 = fmaxf(tn, lb); np0 = pc0; }
      }
    }
    if (S1 <= rad) { t1 = 0.f; d1 = true; }
    else {
      float lb = (S1 - rad) * invD;
      if (pc1 < 0.5f) t1 = lb;
      else {
        float tn = tp1 + __fdividef(psa1 - rad, pc1);
        if (tn == tp1 || fabsf(tn - tp1) <= TOL * tp1) { t1 = tn; d1 = true; }
        else { t1 = fmaxf(tn, lb); np1 = pc1; }
      }
    }
    for (int k = 0; k < maxk && !(d0 && d1); ++k) {
      float sa0 = 0.f, c0 = 0.f, sa1 = 0.f, c1 = 0.f;
      scan(t0, t1, sa0, c0, sa1, c1);
      float4 rd = blk_red4(sa0, c0, sa1, c1);
      if (!d0) {
        if (rd.y < 0.5f) { t0 = (S0 - rad) * invD; np0 = -1.f; }
        else {
          float tn = __fdividef(rd.x - rad, rd.y);
          if (rd.y == np0 || tn == t0 || fabsf(tn - t0) <= TOL * t0) d0 = true;
          t0 = tn; np0 = rd.y;
        }
      }
      if (!d1) {
        if (rd.w < 0.5f) { t1 = (S1 - rad) * invD; np1 = -1.f; }
        else {
          float tn = __fdividef(rd.z - rad, rd.w);
          if (rd.w == np1 || tn == t1 || fabsf(tn - t1) <= TOL * t1) d1 = true;
          t1 = tn; np1 = rd.w;
        }
      }
    }
    return make_float2(t0, t1);
  };

  auto scanP1 = [&](float t0, float t1, float& sa0, float& c0, float& sa1, float& c1) {
#pragma unroll
    for (int di = 0; di < TI; ++di)
#pragma unroll
      for (int dj = 0; dj < TJ; ++dj) {
        f2 w = u[di][dj] - xi[di][dj];
        float a0v = fabsf(w.x);
        float a1v = fabsf(w.y);
        if (a0v > t0) { sa0 += a0v; c0 += 1.f; }
        if (a1v > t1) { sa1 += a1v; c1 += 1.f; }
      }
  };
  auto scanP3 = [&](float t0, float t1, float& sa0, float& c0, float& sa1, float& c1) {
#pragma unroll
    for (int di = 0; di < TI; ++di)
#pragma unroll
      for (int dj = 0; dj < TJ; ++dj) {
        float a0v = fabsf(u[di][dj].x);
        float a1v = fabsf(u[di][dj].y);
        if (a0v > t0) { sa0 += a0v; c0 += 1.f; }
        if (a1v > t1) { sa1 += a1v; c1 += 1.f; }
      }
  };

  float thx, thy;   // current thresholds (captured by div_pass for halo clamp)

  // div: t = m - div(u). hClamp: halos are pre-clamp u_pre -> apply fmed3 at
  // read with (thx for x-comp rows, thy for y-comp cols).
  auto div_pass = [&](bool hClamp) {
#pragma unroll
    for (int di = 0; di < TI; ++di) {
#pragma unroll
      for (int q2 = 0; q2 < 4; ++q2) {
        float2 mm = m2_lds[(di * 4 + q2) * NTHREADS + tid];
        float tt0, tt1;
        {
          const int dj = 2 * q2;
          float up;
          if (di > 0) up = u[di - 1][dj].x;
          else {
            float h = sTop[dj][(ty > 0) ? ty - 1 : 0][tx];
            if (hClamp) h = __builtin_amdgcn_fmed3f(h, -thx, thx);
            up = (ty > 0) ? h : 0.f;
          }
          float lf;
          if (dj > 0) lf = u[di][dj - 1].y;
          else {
            float h = sLeft[di][ty][(tx > 0) ? tx - 1 : 0];
            if (hClamp) h = __builtin_amdgcn_fmed3f(h, -thy, thy);
            lf = (tx > 0) ? h : 0.f;
          }
          float vx = u[di][dj].x; if (di == TI - 1) vx *= mx;
          float vy = u[di][dj].y;
          tt0 = mm.x - ((vx - up) + (vy - lf));
        }
        {
          const int dj = 2 * q2 + 1;
          float up;
          if (di > 0) up = u[di - 1][dj].x;
          else {
            float h = sTop[dj][(ty > 0) ? ty - 1 : 0][tx];
            if (hClamp) h = __builtin_amdgcn_fmed3f(h, -thx, thx);
            up = (ty > 0) ? h : 0.f;
          }
          float lf = u[di][dj - 1].y;
          float vx = u[di][dj].x; if (di == TI - 1) vx *= mx;
          float vy = u[di][dj].y; if (dj == TJ - 1) vy *= my;
          tt1 = mm.y - ((vx - up) + (vy - lf));
        }
        t2_lds[(di * 4 + q2) * NTHREADS + tid] = make_float2(tt0, tt1);
      }
    }
  };

  // grad: strip-walk with rolling window over t2_lds. consume(di,dj,g).
  auto grad_pass = [&](auto&& consume) {
#pragma unroll
    for (int q2 = 0; q2 < 4; ++q2) {
      float2 cur = t2_lds[q2 * NTHREADS + tid];
#pragma unroll
      for (int di = 0; di < TI; ++di) {
        float2 nxt;
        if (di < TI - 1) nxt = t2_lds[((di + 1) * 4 + q2) * NTHREADS + tid];
        else nxt = t2_lds[q2 * NTHREADS + tid + ((ty < GI - 1) ? GJ : 0)];
        float rt1;
        if (q2 < 3) rt1 = t2_lds[(di * 4 + q2 + 1) * NTHREADS + tid].x;
        else rt1 = t2_lds[(di * 4) * NTHREADS + tid + ((tx < GJ - 1) ? 1 : 0)].x;
        {
          f2 g;                              // dj = 2*q2
          g.x = nxt.x - cur.x; if (di == TI - 1) g.x *= mx;
          g.y = cur.y - cur.x;
          consume(di, 2 * q2, g);
        }
        {
          f2 g;                              // dj = 2*q2+1
          g.x = nxt.y - cur.y; if (di == TI - 1) g.x *= mx;
          g.y = rt1 - cur.y;   if (q2 == 3) g.y *= my;
          consume(di, 2 * q2 + 1, g);
        }
        cur = nxt;
      }
    }
  };

  float A = 0.f;
  float h1x = 0.f, h1y = 0.f, d1x = 0.f, d1y = 0.f, d1xp = 0.f, d1yp = 0.f;
  float h3x = 0.f, h3y = 0.f, d3x = 0.f, d3y = 0.f, d3xp = 0.f, d3yp = 0.f;
  float S0p = 0.f, S1p = 0.f, q1s0 = 0.f, q1s1 = 0.f, q1c0 = 0.f, q1c1 = 0.f;
  float t1p0 = 0.f, t1p1 = 0.f;
  const float rad3 = r * (MUc * 0.5f);

#pragma unroll 1
  for (int it = 0; it < NIT; ++it) {
    const float a_ = 0.5f * (MUc + sqrtf(MUc * (MUc + 4.f * A)));
    const int maxk = (it < 8) ? 8 : 0;   // warm-up scans only

    // ---- P1 thresholds
    if (it == 0) { thx = INFINITY; thy = INFINITY; }
    else {
      float2 th = solve2(scanP1, S0p, S1p, r * A,
                         q1s0, q1c0, t1p0, q1s1, q1c1, t1p1, maxk);
      thx = th.x; thy = th.y;
      d1xp = d1x; d1yp = d1y;
      d1x = thx - h1x; d1y = thy - h1y;
      h1x = thx; h1y = thy;
    }

    // ---- P2a: y = cu*u + cv*clamp(u-xi, ±th); write y halos
    {
      const float inv = 1.f / (A + a_);
      const float cu = A * inv, cv = a_ * inv;
#pragma unroll
      for (int di = 0; di < TI; ++di)
#pragma unroll
        for (int dj = 0; dj < TJ; ++dj) {
          f2 w = u[di][dj] - xi[di][dj];
          f2 v;
          v.x = __builtin_amdgcn_fmed3f(w.x, -thx, thx);
          v.y = __builtin_amdgcn_fmed3f(w.y, -thy, thy);
          u[di][dj] = u[di][dj] * cu + v * cv;
        }
#pragma unroll
      for (int dj = 0; dj < TJ; ++dj) sTop[dj][ty][tx] = u[TI - 1][dj].x;
#pragma unroll
      for (int di = 0; di < TI; ++di) sLeft[di][ty][tx] = u[di][TJ - 1].y;
    }
    __syncthreads();
    div_pass(false);       // t = M - div(y)
    __syncthreads();

    // ---- P2b: u_pre = y - (mu/2) grad(t); fused P3 sums + predictive probe;
    //           write u_pre halos (div#2 clamps at read) before red6's barrier
    {
      float s0 = 0.f, s1 = 0.f, p0 = 0.f, p1 = 0.f, c0 = 0.f, c1 = 0.f;
      const float tp0 = fmaxf(0.f, h3x + d3x + (d3x - d3xp));
      const float tp1 = fmaxf(0.f, h3y + d3y + (d3y - d3yp));
      grad_pass([&](int di, int dj, f2 g) {
        f2 nu = u[di][dj] - 0.125f * g;
        u[di][dj] = nu;
        float a0 = fabsf(nu.x), a1 = fabsf(nu.y);
        s0 += a0; s1 += a1;
        if (a0 > tp0) { p0 += a0 - tp0; c0 += 1.f; }
        if (a1 > tp1) { p1 += a1 - tp1; c1 += 1.f; }
      });
#pragma unroll
      for (int dj = 0; dj < TJ; ++dj) sTop[dj][ty][tx] = u[TI - 1][dj].x;  // u_pre
#pragma unroll
      for (int di = 0; di < TI; ++di) sLeft[di][ty][tx] = u[di][TJ - 1].y; // u_pre
      float4 q4; float2 q2;
      blk_red6(s0, s1, p0, p1, c0, c1, q4, q2);  // barrier covers halo writes

      float2 th3 = solve2(scanP3, q4.x, q4.y, rad3,
                          q4.z, q2.x, tp0, q4.w, q2.y, tp1, maxk);
      thx = th3.x; thy = th3.y;
      d3xp = d3x; d3yp = d3y;
      d3x = thx - h3x; d3y = thy - h3y;
      h3x = thx; h3y = thy;
    }
    // ---- P4a: apply clamp (registers only; halos already staged pre-clamp)
#pragma unroll
    for (int di = 0; di < TI; ++di)
#pragma unroll
      for (int dj = 0; dj < TJ; ++dj) {
        u[di][dj].x = __builtin_amdgcn_fmed3f(u[di][dj].x, -thx, thx);
        u[di][dj].y = __builtin_amdgcn_fmed3f(u[di][dj].y, -thy, thy);
      }
    div_pass(true);        // t = Mnew (halos clamped at read); no extra sync
    if (it == NIT - 1) break;
    __syncthreads();

    // ---- P4b: xi += a*grad(Mnew); fused next-P1 sums + predictive probe
    {
      float s0 = 0.f, s1 = 0.f, p0 = 0.f, p1 = 0.f, c0 = 0.f, c1 = 0.f;
      t1p0 = fmaxf(0.f, h1x + d1x + (d1x - d1xp));
      t1p1 = fmaxf(0.f, h1y + d1y + (d1y - d1yp));
      const float tp0 = t1p0, tp1 = t1p1;
      grad_pass([&](int di, int dj, f2 g) {
        xi[di][dj] = xi[di][dj] + a_ * g;
        f2 w = u[di][dj] - xi[di][dj];
        float a0 = fabsf(w.x);
        float a1 = fabsf(w.y);
        s0 += a0; s1 += a1;
        if (a0 > tp0) { p0 += a0 - tp0; c0 += 1.f; }
        if (a1 > tp1) { p1 += a1 - tp1; c1 += 1.f; }
      });
      float4 q4; float2 q2;
      blk_red6(s0, s1, p0, p1, c0, c1, q4, q2);
      S0p = q4.x; S1p = q4.y; q1s0 = q4.z; q1s1 = q4.w; q1c0 = q2.x; q1c1 = q2.y;
    }
    A += a_;
  }

  // outputs: M1 = last Mnew (own t2 entries), u interleaved (last-dim 2)
  float* outM = out + (size_t)b * NN * NN;
  float* outU = out + (size_t)Nb * NN * NN + (size_t)b * NN * NN * 2;
#pragma unroll
  for (int di = 0; di < TI; ++di)
#pragma unroll
    for (int q2 = 0; q2 < 4; ++q2) {
      float2 tp = t2_lds[(di * 4 + q2) * NTHREADS + tid];
      const int idx0 = (i0 + di) * NN + (j0 + 2 * q2);
      outM[idx0]     = tp.x;
      outM[idx0 + 1] = tp.y;
      reinterpret_cast<float2*>(outU)[idx0]     = make_float2(u[di][2 * q2].x,     u[di][2 * q2].y);
      reinterpret_cast<float2*>(outU)[idx0 + 1] = make_float2(u[di][2 * q2 + 1].x, u[di][2 * q2 + 1].y);
    }
}

extern "C" void kernel_launch(void* const* d_in, const int* in_sizes, int n_in,
                              void* d_out, int out_size, void* d_ws, size_t ws_size,
                              hipStream_t stream) {
  const float* M  = (const float*)d_in[0];
  const float* tv = (const float*)d_in[1];
  const int Nb = in_sizes[0] / (NN * NN);   // 8
  tv_kernel<<<dim3(Nb), dim3(NTHREADS), 0, stream>>>(M, tv, (float*)d_out, Nb);
}

// Round 16
// 1752.969 us; speedup vs baseline: 3.3365x; 1.0967x over previous
//
#include <hip/hip_runtime.h>
#include <math.h>

#define NIT 200
#define NN 128
#define TI 4
#define TJ 8
#define GI 32   // NN/TI
#define GJ 16   // NN/TJ
#define NTHREADS 512
#define NWAVES 8

typedef float f2 __attribute__((ext_vector_type(2)));

// one DPP-fused add step: x += dpp_move(x, CTRL); CTRL/RMASK as template
// params (builtin requires integer-constant operands).
template <int CTRL, int RMASK>
__device__ __forceinline__ float dppadd(float x) {
  int v = __builtin_amdgcn_update_dpp(0, __float_as_int(x), CTRL, RMASK, 0xf, true);
  return x + __int_as_float(v);
}
// full wave64 sum; result valid in lane 63 (canonical GCN sequence)
__device__ __forceinline__ float wsum63(float x) {
  x = dppadd<0x111, 0xf>(x);   // row_shr:1
  x = dppadd<0x112, 0xf>(x);   // row_shr:2
  x = dppadd<0x114, 0xf>(x);   // row_shr:4
  x = dppadd<0x118, 0xf>(x);   // row_shr:8
  x = dppadd<0x142, 0xa>(x);   // row_bcast:15
  x = dppadd<0x143, 0xc>(x);   // row_bcast:31
  return x;
}

__global__ __launch_bounds__(NTHREADS)
void tv_kernel(const float* __restrict__ Min, const float* __restrict__ tvr,
               float* __restrict__ out, int Nb)
{
  const float MUc = 0.25f;
  const int b   = blockIdx.x;
  const int tid = threadIdx.x;
  const int tx  = tid & (GJ - 1);   // 0..15
  const int ty  = tid >> 4;         // 0..31
  const int lane = tid & 63;
  const int wv   = tid >> 6;
  const int i0 = ty * TI;
  const int j0 = tx * TJ;

  __shared__ float2 m2_lds[(TI * TJ / 2) * NTHREADS];  // 64 KB
  __shared__ float2 t2_lds[(TI * TJ / 2) * NTHREADS];  // 64 KB
  __shared__ float sTop [TJ][GI][GJ];           // 16 KB  (x-comp bottom rows)
  __shared__ float sLeft[TI][GI][GJ];           //  8 KB  (y-comp right cols)
  __shared__ float4 sRedA[2][NWAVES];           // warm-up red4 slots
  __shared__ float  sRedF[2][6][NWAVES];        // hot red6 slots [par][k][wave]
  // total ~152.5 KB -> 1 block/CU

  const float r = tvr[0];
  const float mx = (ty == GI - 1) ? 0.f : 1.f;
  const float my = (tx == GJ - 1) ? 0.f : 1.f;

  f2 u[TI][TJ], xi[TI][TJ];   // 128 VGPRs of state

  const float* Mb = Min + (size_t)b * NN * NN;
#pragma unroll
  for (int di = 0; di < TI; ++di) {
    float4 v0 = *reinterpret_cast<const float4*>(Mb + (i0 + di) * NN + j0);
    float4 v1 = *reinterpret_cast<const float4*>(Mb + (i0 + di) * NN + j0 + 4);
    m2_lds[(di * 4 + 0) * NTHREADS + tid] = make_float2(v0.x, v0.y);
    m2_lds[(di * 4 + 1) * NTHREADS + tid] = make_float2(v0.z, v0.w);
    m2_lds[(di * 4 + 2) * NTHREADS + tid] = make_float2(v1.x, v1.y);
    m2_lds[(di * 4 + 3) * NTHREADS + tid] = make_float2(v1.z, v1.w);
#pragma unroll
    for (int dj = 0; dj < TJ; ++dj) {
      u[di][dj] = (f2)0.f; xi[di][dj] = (f2)0.f;
    }
  }
  __syncthreads();

  int par = 0;
  // warm-up-only 4-value reduce (scan verification rounds)
  auto blk_red4 = [&](float v0, float v1, float v2, float v3) {
#pragma unroll
    for (int off = 32; off >= 1; off >>= 1) {
      v0 += __shfl_xor(v0, off, 64);
      v1 += __shfl_xor(v1, off, 64);
      v2 += __shfl_xor(v2, off, 64);
      v3 += __shfl_xor(v3, off, 64);
    }
    if (lane == 0) sRedA[par][wv] = make_float4(v0, v1, v2, v3);
    __syncthreads();
    float4 acc = make_float4(0.f, 0.f, 0.f, 0.f);
#pragma unroll
    for (int w = 0; w < NWAVES; ++w) {
      float4 q = sRedA[par][w];
      acc.x += q.x; acc.y += q.y; acc.z += q.z; acc.w += q.w;
    }
    par ^= 1;
    return acc;
  };
  // hot 6-value reduce: DPP wave fold -> [k][wave] slots -> lane-parallel
  // cross-wave butterfly (1 conflict-free b32 read + 3 shfl) -> 6 broadcasts.
  auto blk_red6 = [&](float s0, float s1, float p0, float p1, float c0, float c1,
                      float4& o4, float2& o2) {
    s0 = wsum63(s0); s1 = wsum63(s1);
    p0 = wsum63(p0); p1 = wsum63(p1);
    c0 = wsum63(c0); c1 = wsum63(c1);
    if (lane == 63) {
      sRedF[par][0][wv] = s0; sRedF[par][1][wv] = s1;
      sRedF[par][2][wv] = p0; sRedF[par][3][wv] = p1;
      sRedF[par][4][wv] = c0; sRedF[par][5][wv] = c1;
    }
    __syncthreads();
    float v = (lane < 6 * NWAVES) ? (&sRedF[par][0][0])[lane] : 0.f;
    v += __shfl_xor(v, 1, 64);
    v += __shfl_xor(v, 2, 64);
    v += __shfl_xor(v, 4, 64);   // every lane in 8-group holds its k-total
    o4.x = __shfl(v,  0, 64); o4.y = __shfl(v,  8, 64);
    o4.z = __shfl(v, 16, 64); o4.w = __shfl(v, 24, 64);
    o2.x = __shfl(v, 32, 64); o2.y = __shfl(v, 40, 64);
    par ^= 1;
  };

  // Duchi threshold solve with fused PREDICTIVE probe. maxk>0 (warm-up):
  // verification scans refine to the exact root. maxk==0 (steady state):
  // single Newton step from the probe (exact global sums at the predicted
  // point); with 2nd-order prediction the step error is O(pred_err^2).
  auto solve2 = [&](auto&& scan, float S0, float S1, float rad,
                    float psa0, float pc0, float tp0,
                    float psa1, float pc1, float tp1, int maxk) -> float2 {
    const float invD = 1.f / 16384.f;
    const float TOL = 1e-4f;
    float t0, t1; bool d0 = false, d1 = false;
    float np0 = -1.f, np1 = -1.f;
    if (S0 <= rad) { t0 = 0.f; d0 = true; }
    else {
      float lb = (S0 - rad) * invD;
      if (pc0 < 0.5f) t0 = lb;
      else {
        float tn = tp0 + __fdividef(psa0 - rad, pc0);
        if (tn == tp0 || fabsf(tn - tp0) <= TOL * tp0) { t0 = tn; d0 = true; }
        else { t0 = fmaxf(tn, lb); np0 = pc0; }
      }
    }
    if (S1 <= rad) { t1 = 0.f; d1 = true; }
    else {
      float lb = (S1 - rad) * invD;
      if (pc1 < 0.5f) t1 = lb;
      else {
        float tn = tp1 + __fdividef(psa1 - rad, pc1);
        if (tn == tp1 || fabsf(tn - tp1) <= TOL * tp1) { t1 = tn; d1 = true; }
        else { t1 = fmaxf(tn, lb); np1 = pc1; }
      }
    }
    for (int k = 0; k < maxk && !(d0 && d1); ++k) {
      float sa0 = 0.f, c0 = 0.f, sa1 = 0.f, c1 = 0.f;
      scan(t0, t1, sa0, c0, sa1, c1);
      float4 rd = blk_red4(sa0, c0, sa1, c1);
      if (!d0) {
        if (rd.y < 0.5f) { t0 = (S0 - rad) * invD; np0 = -1.f; }
        else {
          float tn = __fdividef(rd.x - rad, rd.y);
          if (rd.y == np0 || tn == t0 || fabsf(tn - t0) <= TOL * t0) d0 = true;
          t0 = tn; np0 = rd.y;
        }
      }
      if (!d1) {
        if (rd.w < 0.5f) { t1 = (S1 - rad) * invD; np1 = -1.f; }
        else {
          float tn = __fdividef(rd.z - rad, rd.w);
          if (rd.w == np1 || tn == t1 || fabsf(tn - t1) <= TOL * t1) d1 = true;
          t1 = tn; np1 = rd.w;
        }
      }
    }
    return make_float2(t0, t1);
  };

  auto scanP1 = [&](float t0, float t1, float& sa0, float& c0, float& sa1, float& c1) {
#pragma unroll
    for (int di = 0; di < TI; ++di)
#pragma unroll
      for (int dj = 0; dj < TJ; ++dj) {
        f2 w = u[di][dj] - xi[di][dj];
        float a0v = fabsf(w.x);
        float a1v = fabsf(w.y);
        if (a0v > t0) { sa0 += a0v; c0 += 1.f; }
        if (a1v > t1) { sa1 += a1v; c1 += 1.f; }
      }
  };
  auto scanP3 = [&](float t0, float t1, float& sa0, float& c0, float& sa1, float& c1) {
#pragma unroll
    for (int di = 0; di < TI; ++di)
#pragma unroll
      for (int dj = 0; dj < TJ; ++dj) {
        float a0v = fabsf(u[di][dj].x);
        float a1v = fabsf(u[di][dj].y);
        if (a0v > t0) { sa0 += a0v; c0 += 1.f; }
        if (a1v > t1) { sa1 += a1v; c1 += 1.f; }
      }
  };

  float thx, thy;   // current thresholds (captured by div_pass for halo clamp)

  // div: t = m - div(u). hClamp: halos are pre-clamp u_pre -> fmed3 at read.
  auto div_pass = [&](bool hClamp) {
#pragma unroll
    for (int di = 0; di < TI; ++di) {
#pragma unroll
      for (int q2 = 0; q2 < 4; ++q2) {
        float2 mm = m2_lds[(di * 4 + q2) * NTHREADS + tid];
        float tt0, tt1;
        {
          const int dj = 2 * q2;
          float up;
          if (di > 0) up = u[di - 1][dj].x;
          else {
            float h = sTop[dj][(ty > 0) ? ty - 1 : 0][tx];
            if (hClamp) h = __builtin_amdgcn_fmed3f(h, -thx, thx);
            up = (ty > 0) ? h : 0.f;
          }
          float lf;
          if (dj > 0) lf = u[di][dj - 1].y;
          else {
            float h = sLeft[di][ty][(tx > 0) ? tx - 1 : 0];
            if (hClamp) h = __builtin_amdgcn_fmed3f(h, -thy, thy);
            lf = (tx > 0) ? h : 0.f;
          }
          float vx = u[di][dj].x; if (di == TI - 1) vx *= mx;
          float vy = u[di][dj].y;
          tt0 = mm.x - ((vx - up) + (vy - lf));
        }
        {
          const int dj = 2 * q2 + 1;
          float up;
          if (di > 0) up = u[di - 1][dj].x;
          else {
            float h = sTop[dj][(ty > 0) ? ty - 1 : 0][tx];
            if (hClamp) h = __builtin_amdgcn_fmed3f(h, -thx, thx);
            up = (ty > 0) ? h : 0.f;
          }
          float lf = u[di][dj - 1].y;
          float vx = u[di][dj].x; if (di == TI - 1) vx *= mx;
          float vy = u[di][dj].y; if (dj == TJ - 1) vy *= my;
          tt1 = mm.y - ((vx - up) + (vy - lf));
        }
        t2_lds[(di * 4 + q2) * NTHREADS + tid] = make_float2(tt0, tt1);
      }
    }
  };

  // grad: strip-walk with rolling window over t2_lds. consume(di,dj,g).
  auto grad_pass = [&](auto&& consume) {
#pragma unroll
    for (int q2 = 0; q2 < 4; ++q2) {
      float2 cur = t2_lds[q2 * NTHREADS + tid];
#pragma unroll
      for (int di = 0; di < TI; ++di) {
        float2 nxt;
        if (di < TI - 1) nxt = t2_lds[((di + 1) * 4 + q2) * NTHREADS + tid];
        else nxt = t2_lds[q2 * NTHREADS + tid + ((ty < GI - 1) ? GJ : 0)];
        float rt1;
        if (q2 < 3) rt1 = t2_lds[(di * 4 + q2 + 1) * NTHREADS + tid].x;
        else rt1 = t2_lds[(di * 4) * NTHREADS + tid + ((tx < GJ - 1) ? 1 : 0)].x;
        {
          f2 g;                              // dj = 2*q2
          g.x = nxt.x - cur.x; if (di == TI - 1) g.x *= mx;
          g.y = cur.y - cur.x;
          consume(di, 2 * q2, g);
        }
        {
          f2 g;                              // dj = 2*q2+1
          g.x = nxt.y - cur.y; if (di == TI - 1) g.x *= mx;
          g.y = rt1 - cur.y;   if (q2 == 3) g.y *= my;
          consume(di, 2 * q2 + 1, g);
        }
        cur = nxt;
      }
    }
  };

  float A = 0.f;
  float h1x = 0.f, h1y = 0.f, d1x = 0.f, d1y = 0.f, d1xp = 0.f, d1yp = 0.f;
  float h3x = 0.f, h3y = 0.f, d3x = 0.f, d3y = 0.f, d3xp = 0.f, d3yp = 0.f;
  float S0p = 0.f, S1p = 0.f, q1s0 = 0.f, q1s1 = 0.f, q1c0 = 0.f, q1c1 = 0.f;
  float t1p0 = 0.f, t1p1 = 0.f;
  const float rad3 = r * (MUc * 0.5f);

#pragma unroll 1
  for (int it = 0; it < NIT; ++it) {
    const float a_ = 0.5f * (MUc + sqrtf(MUc * (MUc + 4.f * A)));
    const int maxk = (it < 8) ? 8 : 0;   // warm-up scans only

    // ---- P1 thresholds
    if (it == 0) { thx = INFINITY; thy = INFINITY; }
    else {
      float2 th = solve2(scanP1, S0p, S1p, r * A,
                         q1s0, q1c0, t1p0, q1s1, q1c1, t1p1, maxk);
      thx = th.x; thy = th.y;
      d1xp = d1x; d1yp = d1y;
      d1x = thx - h1x; d1y = thy - h1y;
      h1x = thx; h1y = thy;
    }

    // ---- P2a: y = cu*u + cv*clamp(u-xi, ±th); write y halos
    {
      const float inv = 1.f / (A + a_);
      const float cu = A * inv, cv = a_ * inv;
#pragma unroll
      for (int di = 0; di < TI; ++di)
#pragma unroll
        for (int dj = 0; dj < TJ; ++dj) {
          f2 w = u[di][dj] - xi[di][dj];
          f2 v;
          v.x = __builtin_amdgcn_fmed3f(w.x, -thx, thx);
          v.y = __builtin_amdgcn_fmed3f(w.y, -thy, thy);
          u[di][dj] = u[di][dj] * cu + v * cv;
        }
#pragma unroll
      for (int dj = 0; dj < TJ; ++dj) sTop[dj][ty][tx] = u[TI - 1][dj].x;
#pragma unroll
      for (int di = 0; di < TI; ++di) sLeft[di][ty][tx] = u[di][TJ - 1].y;
    }
    __syncthreads();
    div_pass(false);       // t = M - div(y)
    __syncthreads();

    // ---- P2b: u_pre = y - (mu/2) grad(t); fused P3 sums + predictive probe;
    //           write u_pre halos (div#2 clamps at read) before red6's barrier
    {
      float s0 = 0.f, s1 = 0.f, p0 = 0.f, p1 = 0.f, c0 = 0.f, c1 = 0.f;
      const float tp0 = fmaxf(0.f, h3x + d3x + (d3x - d3xp));
      const float tp1 = fmaxf(0.f, h3y + d3y + (d3y - d3yp));
      grad_pass([&](int di, int dj, f2 g) {
        f2 nu = u[di][dj] - 0.125f * g;
        u[di][dj] = nu;
        float a0 = fabsf(nu.x), a1 = fabsf(nu.y);
        s0 += a0; s1 += a1;
        if (a0 > tp0) { p0 += a0 - tp0; c0 += 1.f; }
        if (a1 > tp1) { p1 += a1 - tp1; c1 += 1.f; }
      });
#pragma unroll
      for (int dj = 0; dj < TJ; ++dj) sTop[dj][ty][tx] = u[TI - 1][dj].x;  // u_pre
#pragma unroll
      for (int di = 0; di < TI; ++di) sLeft[di][ty][tx] = u[di][TJ - 1].y; // u_pre
      float4 q4; float2 q2;
      blk_red6(s0, s1, p0, p1, c0, c1, q4, q2);  // barrier covers halo writes

      float2 th3 = solve2(scanP3, q4.x, q4.y, rad3,
                          q4.z, q2.x, tp0, q4.w, q2.y, tp1, maxk);
      thx = th3.x; thy = th3.y;
      d3xp = d3x; d3yp = d3y;
      d3x = thx - h3x; d3y = thy - h3y;
      h3x = thx; h3y = thy;
    }
    // ---- P4a: apply clamp (registers only; halos already staged pre-clamp)
#pragma unroll
    for (int di = 0; di < TI; ++di)
#pragma unroll
      for (int dj = 0; dj < TJ; ++dj) {
        u[di][dj].x = __builtin_amdgcn_fmed3f(u[di][dj].x, -thx, thx);
        u[di][dj].y = __builtin_amdgcn_fmed3f(u[di][dj].y, -thy, thy);
      }
    div_pass(true);        // t = Mnew (halos clamped at read); no extra sync
    if (it == NIT - 1) break;
    __syncthreads();

    // ---- P4b: xi += a*grad(Mnew); fused next-P1 sums + predictive probe
    {
      float s0 = 0.f, s1 = 0.f, p0 = 0.f, p1 = 0.f, c0 = 0.f, c1 = 0.f;
      t1p0 = fmaxf(0.f, h1x + d1x + (d1x - d1xp));
      t1p1 = fmaxf(0.f, h1y + d1y + (d1y - d1yp));
      const float tp0 = t1p0, tp1 = t1p1;
      grad_pass([&](int di, int dj, f2 g) {
        xi[di][dj] = xi[di][dj] + a_ * g;
        f2 w = u[di][dj] - xi[di][dj];
        float a0 = fabsf(w.x);
        float a1 = fabsf(w.y);
        s0 += a0; s1 += a1;
        if (a0 > tp0) { p0 += a0 - tp0; c0 += 1.f; }
        if (a1 > tp1) { p1 += a1 - tp1; c1 += 1.f; }
      });
      float4 q4; float2 q2;
      blk_red6(s0, s1, p0, p1, c0, c1, q4, q2);
      S0p = q4.x; S1p = q4.y; q1s0 = q4.z; q1s1 = q4.w; q1c0 = q2.x; q1c1 = q2.y;
    }
    A += a_;
  }

  // outputs: M1 = last Mnew (own t2 entries), u interleaved (last-dim 2)
  float* outM = out + (size_t)b * NN * NN;
  float* outU = out + (size_t)Nb * NN * NN + (size_t)b * NN * NN * 2;
#pragma unroll
  for (int di = 0; di < TI; ++di)
#pragma unroll
    for (int q2 = 0; q2 < 4; ++q2) {
      float2 tp = t2_lds[(di * 4 + q2) * NTHREADS + tid];
      const int idx0 = (i0 + di) * NN + (j0 + 2 * q2);
      outM[idx0]     = tp.x;
      outM[idx0 + 1] = tp.y;
      reinterpret_cast<float2*>(outU)[idx0]     = make_float2(u[di][2 * q2].x,     u[di][2 * q2].y);
      reinterpret_cast<float2*>(outU)[idx0 + 1] = make_float2(u[di][2 * q2 + 1].x, u[di][2 * q2 + 1].y);
    }
}

extern "C" void kernel_launch(void* const* d_in, const int* in_sizes, int n_in,
                              void* d_out, int out_size, void* d_ws, size_t ws_size,
                              hipStream_t stream) {
  const float* M  = (const float*)d_in[0];
  const float* tv = (const float*)d_in[1];
  const int Nb = in_sizes[0] / (NN * NN);   // 8
  tv_kernel<<<dim3(Nb), dim3(NTHREADS), 0, stream>>>(M, tv, (float*)d_out, Nb);
}